// Round 2
// baseline (3536.301 us; speedup 1.0000x reference)
//
#include <hip/hip_runtime.h>

#define NN     100000
#define EE     3200000
#define NF     512
#define HIDN   64
#define NCLS   64
#define ALPHA  0.1f

#define NC     4                        // class chunks
#define CW     16                       // classes per chunk (NC*CW = 64)

#define CHUNK  512                      // elements per scan block
#define NB     196                      // ceil(NN / CHUNK)

#define SC_BLOCKS 2048                  // persistent scatter grid

typedef unsigned short ushort_t;
typedef unsigned int   uint_t;

__device__ inline ushort_t f2bf(float f)   // fp32 -> bf16 RTN-even
{
    uint_t u = __float_as_uint(f);
    u += 0x7FFFu + ((u >> 16) & 1u);
    return (ushort_t)(u >> 16);
}
__device__ inline float bf2f(ushort_t b)
{
    return __uint_as_float(((uint_t)b) << 16);
}

// nt 8B edge load: csr is a stream, keep it out of L2 so the 3.2MB chunk
// table keeps per-XCD L2 residency (csr itself stays L3-resident).
__device__ inline int2 ldnt_e(const int2* p)
{
    unsigned long long v =
        __builtin_nontemporal_load((const unsigned long long*)p);
    int2 r;
    r.x = (int)(v & 0xFFFFFFFFull);
    r.y = (int)(v >> 32);
    return r;
}
__device__ inline ushort_t ldnt_u16(const ushort_t* p)
{
    return __builtin_nontemporal_load(p);
}

// ---------------------------------------------------------------------------
// Tiled fp32 GEMM: C[nrows x 64] = act(A[nrows x K] @ B[K x 64])  (fp32 out)
// ---------------------------------------------------------------------------
template <bool RELU>
__global__ __launch_bounds__(256) void gemm_kernel(
    const float* __restrict__ A, const float* __restrict__ B,
    float* __restrict__ C, int nrows, int K)
{
    const int BK = 16;
    __shared__ float AsT[BK][68];
    __shared__ float Bs [BK][68];

    int tid = threadIdx.x;
    int tx  = tid & 15;
    int ty  = tid >> 4;
    int rowBase = blockIdx.x * 64;

    int arow = tid >> 2;
    int ak   = (tid & 3) * 4;
    int brow = tid >> 4;
    int bcol = (tid & 15) * 4;

    float acc[4][4] = {};

    for (int k0 = 0; k0 < K; k0 += BK) {
        float4 av;
        int gr = rowBase + arow;
        if (gr < nrows) av = *(const float4*)(A + (size_t)gr * K + k0 + ak);
        else            av = make_float4(0.f, 0.f, 0.f, 0.f);
        float4 bv = *(const float4*)(B + (size_t)(k0 + brow) * 64 + bcol);

        __syncthreads();
        AsT[ak + 0][arow] = av.x;
        AsT[ak + 1][arow] = av.y;
        AsT[ak + 2][arow] = av.z;
        AsT[ak + 3][arow] = av.w;
        *(float4*)&Bs[brow][bcol] = bv;
        __syncthreads();

#pragma unroll
        for (int kk = 0; kk < BK; ++kk) {
            float4 a = *(const float4*)&AsT[kk][ty * 4];
            float4 b = *(const float4*)&Bs [kk][tx * 4];
            acc[0][0] = fmaf(a.x, b.x, acc[0][0]);
            acc[0][1] = fmaf(a.x, b.y, acc[0][1]);
            acc[0][2] = fmaf(a.x, b.z, acc[0][2]);
            acc[0][3] = fmaf(a.x, b.w, acc[0][3]);
            acc[1][0] = fmaf(a.y, b.x, acc[1][0]);
            acc[1][1] = fmaf(a.y, b.y, acc[1][1]);
            acc[1][2] = fmaf(a.y, b.z, acc[1][2]);
            acc[1][3] = fmaf(a.y, b.w, acc[1][3]);
            acc[2][0] = fmaf(a.z, b.x, acc[2][0]);
            acc[2][1] = fmaf(a.z, b.y, acc[2][1]);
            acc[2][2] = fmaf(a.z, b.z, acc[2][2]);
            acc[2][3] = fmaf(a.z, b.w, acc[2][3]);
            acc[3][0] = fmaf(a.w, b.x, acc[3][0]);
            acc[3][1] = fmaf(a.w, b.y, acc[3][1]);
            acc[3][2] = fmaf(a.w, b.z, acc[3][2]);
            acc[3][3] = fmaf(a.w, b.w, acc[3][3]);
        }
    }

#pragma unroll
    for (int i = 0; i < 4; ++i) {
        int r = rowBase + ty * 4 + i;
        if (r < nrows) {
            float4 o;
            o.x = acc[i][0]; o.y = acc[i][1]; o.z = acc[i][2]; o.w = acc[i][3];
            if (RELU) {
                o.x = fmaxf(o.x, 0.f); o.y = fmaxf(o.y, 0.f);
                o.z = fmaxf(o.z, 0.f); o.w = fmaxf(o.w, 0.f);
            }
            *(float4*)(C + (size_t)r * 64 + tx * 4) = o;
        }
    }
}

// ---------------------------------------------------------------------------
// GEMM2 with fused epilogue writing CHUNKED layouts:
//   zb[c][n][16] = bf16(z0), az[c][n][16] = bf16(ALPHA*z0)
// ---------------------------------------------------------------------------
__global__ __launch_bounds__(256) void gemm2_kernel(
    const float* __restrict__ A, const float* __restrict__ B,
    ushort_t* __restrict__ zb, ushort_t* __restrict__ az, int nrows, int K)
{
    const int BK = 16;
    __shared__ float AsT[BK][68];
    __shared__ float Bs [BK][68];

    int tid = threadIdx.x;
    int tx  = tid & 15;
    int ty  = tid >> 4;
    int rowBase = blockIdx.x * 64;

    int arow = tid >> 2;
    int ak   = (tid & 3) * 4;
    int brow = tid >> 4;
    int bcol = (tid & 15) * 4;

    float acc[4][4] = {};

    for (int k0 = 0; k0 < K; k0 += BK) {
        float4 av;
        int gr = rowBase + arow;
        if (gr < nrows) av = *(const float4*)(A + (size_t)gr * K + k0 + ak);
        else            av = make_float4(0.f, 0.f, 0.f, 0.f);
        float4 bv = *(const float4*)(B + (size_t)(k0 + brow) * 64 + bcol);

        __syncthreads();
        AsT[ak + 0][arow] = av.x;
        AsT[ak + 1][arow] = av.y;
        AsT[ak + 2][arow] = av.z;
        AsT[ak + 3][arow] = av.w;
        *(float4*)&Bs[brow][bcol] = bv;
        __syncthreads();

#pragma unroll
        for (int kk = 0; kk < BK; ++kk) {
            float4 a = *(const float4*)&AsT[kk][ty * 4];
            float4 b = *(const float4*)&Bs [kk][tx * 4];
            acc[0][0] = fmaf(a.x, b.x, acc[0][0]);
            acc[0][1] = fmaf(a.x, b.y, acc[0][1]);
            acc[0][2] = fmaf(a.x, b.z, acc[0][2]);
            acc[0][3] = fmaf(a.x, b.w, acc[0][3]);
            acc[1][0] = fmaf(a.y, b.x, acc[1][0]);
            acc[1][1] = fmaf(a.y, b.y, acc[1][1]);
            acc[1][2] = fmaf(a.y, b.z, acc[1][2]);
            acc[1][3] = fmaf(a.y, b.w, acc[1][3]);
            acc[2][0] = fmaf(a.z, b.x, acc[2][0]);
            acc[2][1] = fmaf(a.z, b.y, acc[2][1]);
            acc[2][2] = fmaf(a.z, b.z, acc[2][2]);
            acc[2][3] = fmaf(a.z, b.w, acc[2][3]);
            acc[3][0] = fmaf(a.w, b.x, acc[3][0]);
            acc[3][1] = fmaf(a.w, b.y, acc[3][1]);
            acc[3][2] = fmaf(a.w, b.z, acc[3][2]);
            acc[3][3] = fmaf(a.w, b.w, acc[3][3]);
        }
    }

    // chunked write: classes tx*4..tx*4+3 -> chunk tx>>2, offset (tx&3)*4
    int c = tx >> 2;
    int k = (tx & 3) * 4;
#pragma unroll
    for (int i = 0; i < 4; ++i) {
        int r = rowBase + ty * 4 + i;
        if (r < nrows) {
            ushort4 o, oa;
            o.x  = f2bf(acc[i][0]);         o.y  = f2bf(acc[i][1]);
            o.z  = f2bf(acc[i][2]);         o.w  = f2bf(acc[i][3]);
            oa.x = f2bf(ALPHA * acc[i][0]); oa.y = f2bf(ALPHA * acc[i][1]);
            oa.z = f2bf(ALPHA * acc[i][2]); oa.w = f2bf(ALPHA * acc[i][3]);
            size_t o16 = (size_t)c * (NN * CW) + (size_t)r * CW + k;
            *(ushort4*)(zb + o16) = o;
            *(ushort4*)(az + o16) = oa;
        }
    }
}

// ---------------------------------------------------------------------------
// CSR construction (per-node cursors)
// ---------------------------------------------------------------------------
__global__ __launch_bounds__(256) void zero_kernel(int* __restrict__ p, int n)
{
    int i = blockIdx.x * 256 + threadIdx.x;
    if (i < n) p[i] = 0;
}

__global__ __launch_bounds__(256) void count_kernel(const int* __restrict__ dst,
                                                    int* __restrict__ deg)
{
    int e = blockIdx.x * 256 + threadIdx.x;
    if (e < EE) atomicAdd(&deg[dst[e]], 1);
}

__global__ __launch_bounds__(256) void scanA_kernel(const int* __restrict__ deg,
                                                    int* __restrict__ bsum)
{
    int b = blockIdx.x, t = threadIdx.x;
    int i = b * CHUNK + t * 2;
    int v = 0;
    if (i < NN)     v += deg[i];
    if (i + 1 < NN) v += deg[i + 1];
    __shared__ int sm[256];
    sm[t] = v;
    __syncthreads();
    for (int o = 128; o > 0; o >>= 1) {
        if (t < o) sm[t] += sm[t + o];
        __syncthreads();
    }
    if (t == 0) bsum[b] = sm[0];
}

__global__ __launch_bounds__(256) void scanB_kernel(const int* __restrict__ bsum,
                                                    int* __restrict__ bbase,
                                                    int* __restrict__ offs)
{
    int t = threadIdx.x;
    int v = (t < NB) ? bsum[t] : 0;
    __shared__ int sm[256];
    sm[t] = v;
    __syncthreads();
    for (int o = 1; o < 256; o <<= 1) {
        int u = (t >= o) ? sm[t - o] : 0;
        __syncthreads();
        sm[t] += u;
        __syncthreads();
    }
    if (t < NB) bbase[t] = sm[t] - v;
    if (t == 0) offs[NN] = EE;
}

__global__ __launch_bounds__(256) void scanC_kernel(const int* __restrict__ deg,
                                                    const int* __restrict__ bbase,
                                                    int* __restrict__ offs,
                                                    int* __restrict__ cursor)
{
    int b = blockIdx.x, t = threadIdx.x;
    int i0 = b * CHUNK + t * 2;
    int d0 = (i0 < NN)     ? deg[i0]     : 0;
    int d1 = (i0 + 1 < NN) ? deg[i0 + 1] : 0;
    int local = d0 + d1;
    __shared__ int sm[256];
    sm[t] = local;
    __syncthreads();
    for (int o = 1; o < 256; o <<= 1) {
        int u = (t >= o) ? sm[t - o] : 0;
        __syncthreads();
        sm[t] += u;
        __syncthreads();
    }
    int excl = sm[t] - local + bbase[b];
    if (i0 < NN)     { offs[i0]     = excl;      cursor[i0]     = excl;      }
    if (i0 + 1 < NN) { offs[i0 + 1] = excl + d0; cursor[i0 + 1] = excl + d0; }
}

__global__ __launch_bounds__(256) void scatter_kernel(
    const int* __restrict__ src, const int* __restrict__ dst,
    const float* __restrict__ w, int* cursor, int2* __restrict__ csr)
{
    const int x      = blockIdx.x & 7;
    const int lo     = x * (NN / 8);
    const int hi     = lo + (NN / 8);
    const int nsl    = gridDim.x >> 3;
    const int stride = nsl * 256;
    for (int e = (blockIdx.x >> 3) * 256 + threadIdx.x; e < EE; e += stride) {
        int d = dst[e];
        if (d >= lo && d < hi) {
            int pos = atomicAdd(&cursor[d], 1);
            csr[pos] = make_int2(src[e], __float_as_int(w[e]));
        }
    }
}

// ---------------------------------------------------------------------------
// Chunked APPNP propagation.
// z layout [NC][NN][CW] bf16: each chunk table is 3.2MB -> fits per-XCD L2.
// blockIdx%8 -> XCD round-robin: XCD pair {2c,2c+1} only processes chunk c,
// so each L2 holds exactly one chunk table; gathers become L2 hits instead
// of ~3.3TB/s random-64B L3 fabric traffic.
// Wave = 1 node: lane = eslot(lane>>4) * class(lane&15); 4 edges in parallel,
// each 16-lane group gathers a contiguous 32B row slice.
// ---------------------------------------------------------------------------
template <bool FINAL>
__global__ __launch_bounds__(256) void propagate_kernel(
    const ushort_t* __restrict__ zin,   // [NC][NN][CW] bf16
    const ushort_t* __restrict__ az0,   // [NC][NN][CW] bf16
    ushort_t* __restrict__ zout,        // [NC][NN][CW] bf16   (!FINAL)
    float* __restrict__ zf,             // [NC][NN][CW] fp32   (FINAL)
    const int* __restrict__ offs, const int2* __restrict__ csr)
{
    int bid   = blockIdx.x;
    int xcd   = bid & 7;
    int c     = xcd >> 1;
    int half  = xcd & 1;
    int g     = bid >> 3;                       // 0..12499
    int wave  = threadIdx.x >> 6;
    int lane  = threadIdx.x & 63;
    int node  = ((g * 2 + half) << 2) + wave;   // covers [0, NN) per chunk
    int cls   = lane & 15;
    int eslot = lane >> 4;

    const ushort_t* zt = zin + (size_t)c * (NN * CW);

    int beg = offs[node];
    int end = offs[node + 1];
    float acc = 0.f;
    int j = beg;
    for (; j + 8 <= end; j += 8) {
        int2 e0 = ldnt_e(csr + j + eslot);
        int2 e1 = ldnt_e(csr + j + 4 + eslot);
        float v0 = bf2f(zt[(size_t)e0.x * CW + cls]);
        float v1 = bf2f(zt[(size_t)e1.x * CW + cls]);
        acc = fmaf(__int_as_float(e0.y), v0, acc);
        acc = fmaf(__int_as_float(e1.y), v1, acc);
    }
    if (j + 4 <= end) {
        int2 e = ldnt_e(csr + j + eslot);
        acc = fmaf(__int_as_float(e.y), bf2f(zt[(size_t)e.x * CW + cls]), acc);
        j += 4;
    }
    int r = end - j;
    if (eslot < r) {
        int2 e = ldnt_e(csr + j + eslot);
        acc = fmaf(__int_as_float(e.y), bf2f(zt[(size_t)e.x * CW + cls]), acc);
    }
    // reduce the 4 edge-slot partials; every lane ends with the class total
    acc += __shfl_xor(acc, 16, 64);
    acc += __shfl_xor(acc, 32, 64);

    size_t o16 = (size_t)c * (NN * CW) + (size_t)node * CW + cls;
    float out = acc + bf2f(ldnt_u16(az0 + o16));
    if (eslot == 0) {
        if (FINAL) zf[o16] = out;
        else       __builtin_nontemporal_store(f2bf(out), zout + o16);
    }
}

// log_softmax over the 4 chunks; IN = float (fp32 path) or ushort_t (bf16)
template <typename T>
__global__ __launch_bounds__(256) void lsm_kernel(
    const T* __restrict__ zf, float* __restrict__ out)
{
    int gid  = blockIdx.x * 256 + threadIdx.x;
    int node = gid >> 6;
    int lane = gid & 63;
    if (node >= NN) return;
    size_t o16 = (size_t)(lane >> 4) * (NN * CW) + (size_t)node * CW + (lane & 15);
    float v;
    if (sizeof(T) == 2) v = bf2f(*(const ushort_t*)(zf + o16));
    else                v = *(const float*)(zf + o16);
    float m = v;
#pragma unroll
    for (int o = 32; o > 0; o >>= 1) m = fmaxf(m, __shfl_xor(m, o, 64));
    float e = __expf(v - m);
    float s = e;
#pragma unroll
    for (int o = 32; o > 0; o >>= 1) s += __shfl_xor(s, o, 64);
    out[(size_t)node * 64 + lane] = (v - m) - __logf(s);
}

// ---------------------------------------------------------------------------
extern "C" void kernel_launch(void* const* d_in, const int* in_sizes, int n_in,
                              void* d_out, int out_size, void* d_ws, size_t ws_size,
                              hipStream_t stream)
{
    const float* x  = (const float*)d_in[0];
    const int*   ei = (const int*)  d_in[1];
    const float* ew = (const float*)d_in[2];
    const float* W1 = (const float*)d_in[3];
    const float* W2 = (const float*)d_in[4];
    const int* src = ei;
    const int* dst = ei + EE;

    char* ws = (char*)d_ws;
    size_t off = 0;
    auto alloc = [&](size_t bytes) -> char* {
        char* p = ws + off;
        off += (bytes + 255) & ~(size_t)255;
        return p;
    };

    float*    h     = (float*)   alloc((size_t)NN * HIDN * 4);  // 25.6 MB; -> csr
    ushort_t* zbA   = (ushort_t*)alloc((size_t)NN * NCLS * 2);  // 12.8 MB chunked z0
    ushort_t* zbB   = (ushort_t*)alloc((size_t)NN * NCLS * 2);  // 12.8 MB
    ushort_t* az0   = (ushort_t*)alloc((size_t)NN * NCLS * 2);  // 12.8 MB chunked a*z0
    int*      deg   = (int*)     alloc((size_t)NN * 4);
    int*      offs  = (int*)     alloc((size_t)(NN + 1) * 4);
    int*      cur_  = (int*)     alloc((size_t)NN * 4);
    int*      bsum  = (int*)     alloc((size_t)NB * 4);
    int*      bbase = (int*)     alloc((size_t)NB * 4);
    size_t base_need = off;
    float*    zf    = (float*)   alloc((size_t)NN * NCLS * 4);  // 25.6 MB fp32 final
    bool use_f32 = (off <= ws_size);    // ws-guard: fall back to bf16 final
    (void)base_need;

    int2* csr = (int2*)h;       // h dead after GEMM2

    // feature transform (gemm2 fuses chunked bf16 z0 + alpha*z0 epilogue)
    gemm_kernel<true><<<(NN + 63) / 64, 256, 0, stream>>>(x, W1, h, NN, NF);
    gemm2_kernel<<<(NN + 63) / 64, 256, 0, stream>>>(h, W2, zbA, az0, NN, HIDN);

    // CSR build
    zero_kernel<<<(NN + 255) / 256, 256, 0, stream>>>(deg, NN);
    count_kernel<<<EE / 256, 256, 0, stream>>>(dst, deg);
    scanA_kernel<<<NB, 256, 0, stream>>>(deg, bsum);
    scanB_kernel<<<1, 256, 0, stream>>>(bsum, bbase, offs);
    scanC_kernel<<<NB, 256, 0, stream>>>(deg, bbase, offs, cur_);
    scatter_kernel<<<SC_BLOCKS, 256, 0, stream>>>(src, dst, ew, cur_, csr);

    // 10 chunked power iterations (grid = NC * NN/4 blocks, 4 nodes/block)
    const int PG = NC * (NN / 4);       // 100000 blocks
    const ushort_t* cur = zbA;
    ushort_t* nxt = zbB;
    for (int it = 0; it < 9; ++it) {
        propagate_kernel<false><<<PG, 256, 0, stream>>>(
            cur, az0, nxt, nullptr, offs, csr);
        ushort_t* t = (ushort_t*)cur; cur = nxt; nxt = t;
    }
    if (use_f32) {
        propagate_kernel<true><<<PG, 256, 0, stream>>>(
            cur, az0, nullptr, zf, offs, csr);
        lsm_kernel<float><<<(NN * 64) / 256, 256, 0, stream>>>(zf, (float*)d_out);
    } else {
        propagate_kernel<false><<<PG, 256, 0, stream>>>(
            cur, az0, nxt, nullptr, offs, csr);
        lsm_kernel<ushort_t><<<(NN * 64) / 256, 256, 0, stream>>>(
            nxt, (float*)d_out);
    }
}

// Round 5
// 1860.032 us; speedup vs baseline: 1.9012x; 1.9012x over previous
//
#include <hip/hip_runtime.h>

#define NN     100000
#define EE     3200000
#define NF     512
#define HIDN   64
#define NCLS   64
#define ALPHA  0.1f

#define CHUNK  512                      // elements per scan block
#define NB     196                      // ceil(NN / CHUNK)

#define SC_BLOCKS 2048                  // persistent scatter grid

typedef unsigned short ushort_t;
typedef unsigned int   uint_t;

__device__ inline ushort_t f2bf(float f)   // fp32 -> bf16 RTN-even
{
    uint_t u = __float_as_uint(f);
    u += 0x7FFFu + ((u >> 16) & 1u);
    return (ushort_t)(u >> 16);
}
__device__ inline float bf2f(ushort_t b)
{
    return __uint_as_float(((uint_t)b) << 16);
}

// nt 8B edge load: csr is a zero-reuse stream; keep it out of L2 so gather
// lines of the z table keep residency. (nt LOADS only — round-1 showed nt
// STORES on zout evict next-iteration's gather table: -300us/iter.)
__device__ inline int2 ldnt_e(const int2* p)
{
    unsigned long long v =
        __builtin_nontemporal_load((const unsigned long long*)p);
    int2 r;
    r.x = (int)(v & 0xFFFFFFFFull);
    r.y = (int)(v >> 32);
    return r;
}

// ---------------------------------------------------------------------------
// Tiled fp32 GEMM: C[nrows x 64] = act(A[nrows x K] @ B[K x 64])  (fp32 out)
// ---------------------------------------------------------------------------
template <bool RELU>
__global__ __launch_bounds__(256) void gemm_kernel(
    const float* __restrict__ A, const float* __restrict__ B,
    float* __restrict__ C, int nrows, int K)
{
    const int BK = 16;
    __shared__ float AsT[BK][68];
    __shared__ float Bs [BK][68];

    int tid = threadIdx.x;
    int tx  = tid & 15;
    int ty  = tid >> 4;
    int rowBase = blockIdx.x * 64;

    int arow = tid >> 2;
    int ak   = (tid & 3) * 4;
    int brow = tid >> 4;
    int bcol = (tid & 15) * 4;

    float acc[4][4] = {};

    for (int k0 = 0; k0 < K; k0 += BK) {
        float4 av;
        int gr = rowBase + arow;
        if (gr < nrows) av = *(const float4*)(A + (size_t)gr * K + k0 + ak);
        else            av = make_float4(0.f, 0.f, 0.f, 0.f);
        float4 bv = *(const float4*)(B + (size_t)(k0 + brow) * 64 + bcol);

        __syncthreads();
        AsT[ak + 0][arow] = av.x;
        AsT[ak + 1][arow] = av.y;
        AsT[ak + 2][arow] = av.z;
        AsT[ak + 3][arow] = av.w;
        *(float4*)&Bs[brow][bcol] = bv;
        __syncthreads();

#pragma unroll
        for (int kk = 0; kk < BK; ++kk) {
            float4 a = *(const float4*)&AsT[kk][ty * 4];
            float4 b = *(const float4*)&Bs [kk][tx * 4];
            acc[0][0] = fmaf(a.x, b.x, acc[0][0]);
            acc[0][1] = fmaf(a.x, b.y, acc[0][1]);
            acc[0][2] = fmaf(a.x, b.z, acc[0][2]);
            acc[0][3] = fmaf(a.x, b.w, acc[0][3]);
            acc[1][0] = fmaf(a.y, b.x, acc[1][0]);
            acc[1][1] = fmaf(a.y, b.y, acc[1][1]);
            acc[1][2] = fmaf(a.y, b.z, acc[1][2]);
            acc[1][3] = fmaf(a.y, b.w, acc[1][3]);
            acc[2][0] = fmaf(a.z, b.x, acc[2][0]);
            acc[2][1] = fmaf(a.z, b.y, acc[2][1]);
            acc[2][2] = fmaf(a.z, b.z, acc[2][2]);
            acc[2][3] = fmaf(a.z, b.w, acc[2][3]);
            acc[3][0] = fmaf(a.w, b.x, acc[3][0]);
            acc[3][1] = fmaf(a.w, b.y, acc[3][1]);
            acc[3][2] = fmaf(a.w, b.z, acc[3][2]);
            acc[3][3] = fmaf(a.w, b.w, acc[3][3]);
        }
    }

#pragma unroll
    for (int i = 0; i < 4; ++i) {
        int r = rowBase + ty * 4 + i;
        if (r < nrows) {
            float4 o;
            o.x = acc[i][0]; o.y = acc[i][1]; o.z = acc[i][2]; o.w = acc[i][3];
            if (RELU) {
                o.x = fmaxf(o.x, 0.f); o.y = fmaxf(o.y, 0.f);
                o.z = fmaxf(o.z, 0.f); o.w = fmaxf(o.w, 0.f);
            }
            *(float4*)(C + (size_t)r * 64 + tx * 4) = o;
        }
    }
}

// ---------------------------------------------------------------------------
// GEMM2 with fused epilogue (row-major): zb[n][64] = bf16(z0),
// az[n][64] = bf16(ALPHA*z0). fp32 z0 never hits memory.
// ---------------------------------------------------------------------------
__global__ __launch_bounds__(256) void gemm2_kernel(
    const float* __restrict__ A, const float* __restrict__ B,
    ushort_t* __restrict__ zb, ushort_t* __restrict__ az, int nrows, int K)
{
    const int BK = 16;
    __shared__ float AsT[BK][68];
    __shared__ float Bs [BK][68];

    int tid = threadIdx.x;
    int tx  = tid & 15;
    int ty  = tid >> 4;
    int rowBase = blockIdx.x * 64;

    int arow = tid >> 2;
    int ak   = (tid & 3) * 4;
    int brow = tid >> 4;
    int bcol = (tid & 15) * 4;

    float acc[4][4] = {};

    for (int k0 = 0; k0 < K; k0 += BK) {
        float4 av;
        int gr = rowBase + arow;
        if (gr < nrows) av = *(const float4*)(A + (size_t)gr * K + k0 + ak);
        else            av = make_float4(0.f, 0.f, 0.f, 0.f);
        float4 bv = *(const float4*)(B + (size_t)(k0 + brow) * 64 + bcol);

        __syncthreads();
        AsT[ak + 0][arow] = av.x;
        AsT[ak + 1][arow] = av.y;
        AsT[ak + 2][arow] = av.z;
        AsT[ak + 3][arow] = av.w;
        *(float4*)&Bs[brow][bcol] = bv;
        __syncthreads();

#pragma unroll
        for (int kk = 0; kk < BK; ++kk) {
            float4 a = *(const float4*)&AsT[kk][ty * 4];
            float4 b = *(const float4*)&Bs [kk][tx * 4];
            acc[0][0] = fmaf(a.x, b.x, acc[0][0]);
            acc[0][1] = fmaf(a.x, b.y, acc[0][1]);
            acc[0][2] = fmaf(a.x, b.z, acc[0][2]);
            acc[0][3] = fmaf(a.x, b.w, acc[0][3]);
            acc[1][0] = fmaf(a.y, b.x, acc[1][0]);
            acc[1][1] = fmaf(a.y, b.y, acc[1][1]);
            acc[1][2] = fmaf(a.y, b.z, acc[1][2]);
            acc[1][3] = fmaf(a.y, b.w, acc[1][3]);
            acc[2][0] = fmaf(a.z, b.x, acc[2][0]);
            acc[2][1] = fmaf(a.z, b.y, acc[2][1]);
            acc[2][2] = fmaf(a.z, b.z, acc[2][2]);
            acc[2][3] = fmaf(a.z, b.w, acc[2][3]);
            acc[3][0] = fmaf(a.w, b.x, acc[3][0]);
            acc[3][1] = fmaf(a.w, b.y, acc[3][1]);
            acc[3][2] = fmaf(a.w, b.z, acc[3][2]);
            acc[3][3] = fmaf(a.w, b.w, acc[3][3]);
        }
    }

#pragma unroll
    for (int i = 0; i < 4; ++i) {
        int r = rowBase + ty * 4 + i;
        if (r < nrows) {
            ushort4 o, oa;
            o.x  = f2bf(acc[i][0]);         o.y  = f2bf(acc[i][1]);
            o.z  = f2bf(acc[i][2]);         o.w  = f2bf(acc[i][3]);
            oa.x = f2bf(ALPHA * acc[i][0]); oa.y = f2bf(ALPHA * acc[i][1]);
            oa.z = f2bf(ALPHA * acc[i][2]); oa.w = f2bf(ALPHA * acc[i][3]);
            *(ushort4*)(zb + (size_t)r * 64 + tx * 4) = o;
            *(ushort4*)(az + (size_t)r * 64 + tx * 4) = oa;
        }
    }
}

// ---------------------------------------------------------------------------
// CSR construction (per-node cursors)
// ---------------------------------------------------------------------------
__global__ __launch_bounds__(256) void zero_kernel(int* __restrict__ p, int n)
{
    int i = blockIdx.x * 256 + threadIdx.x;
    if (i < n) p[i] = 0;
}

__global__ __launch_bounds__(256) void count_kernel(const int* __restrict__ dst,
                                                    int* __restrict__ deg)
{
    int e = blockIdx.x * 256 + threadIdx.x;
    if (e < EE) atomicAdd(&deg[dst[e]], 1);
}

__global__ __launch_bounds__(256) void scanA_kernel(const int* __restrict__ deg,
                                                    int* __restrict__ bsum)
{
    int b = blockIdx.x, t = threadIdx.x;
    int i = b * CHUNK + t * 2;
    int v = 0;
    if (i < NN)     v += deg[i];
    if (i + 1 < NN) v += deg[i + 1];
    __shared__ int sm[256];
    sm[t] = v;
    __syncthreads();
    for (int o = 128; o > 0; o >>= 1) {
        if (t < o) sm[t] += sm[t + o];
        __syncthreads();
    }
    if (t == 0) bsum[b] = sm[0];
}

__global__ __launch_bounds__(256) void scanB_kernel(const int* __restrict__ bsum,
                                                    int* __restrict__ bbase,
                                                    int* __restrict__ offs)
{
    int t = threadIdx.x;
    int v = (t < NB) ? bsum[t] : 0;
    __shared__ int sm[256];
    sm[t] = v;
    __syncthreads();
    for (int o = 1; o < 256; o <<= 1) {
        int u = (t >= o) ? sm[t - o] : 0;
        __syncthreads();
        sm[t] += u;
        __syncthreads();
    }
    if (t < NB) bbase[t] = sm[t] - v;
    if (t == 0) offs[NN] = EE;
}

__global__ __launch_bounds__(256) void scanC_kernel(const int* __restrict__ deg,
                                                    const int* __restrict__ bbase,
                                                    int* __restrict__ offs,
                                                    int* __restrict__ cursor)
{
    int b = blockIdx.x, t = threadIdx.x;
    int i0 = b * CHUNK + t * 2;
    int d0 = (i0 < NN)     ? deg[i0]     : 0;
    int d1 = (i0 + 1 < NN) ? deg[i0 + 1] : 0;
    int local = d0 + d1;
    __shared__ int sm[256];
    sm[t] = local;
    __syncthreads();
    for (int o = 1; o < 256; o <<= 1) {
        int u = (t >= o) ? sm[t - o] : 0;
        __syncthreads();
        sm[t] += u;
        __syncthreads();
    }
    int excl = sm[t] - local + bbase[b];
    if (i0 < NN)     { offs[i0]     = excl;      cursor[i0]     = excl;      }
    if (i0 + 1 < NN) { offs[i0 + 1] = excl + d0; cursor[i0 + 1] = excl + d0; }
}

__global__ __launch_bounds__(256) void scatter_kernel(
    const int* __restrict__ src, const int* __restrict__ dst,
    const float* __restrict__ w, int* cursor, int2* __restrict__ csr)
{
    const int x      = blockIdx.x & 7;
    const int lo     = x * (NN / 8);
    const int hi     = lo + (NN / 8);
    const int nsl    = gridDim.x >> 3;
    const int stride = nsl * 256;
    for (int e = (blockIdx.x >> 3) * 256 + threadIdx.x; e < EE; e += stride) {
        int d = dst[e];
        if (d >= lo && d < hi) {
            int pos = atomicAdd(&cursor[d], 1);
            csr[pos] = make_int2(src[e], __float_as_int(w[e]));
        }
    }
}

// ---------------------------------------------------------------------------
// APPNP propagation: round-0 structure (8-deep gather pipeline, plain
// launch bounds — the (256,8) variant failed to bench twice). One wave per
// dst node, lane = class. bf16 z, fp32 acc. Plain temporal loads/stores for
// z/az0/zout (zout is next iteration's gather table); nt only on csr.
// ---------------------------------------------------------------------------
template <bool LSM>
__global__ __launch_bounds__(256) void propagate_kernel(
    const ushort_t* __restrict__ zin, const ushort_t* __restrict__ az0,
    ushort_t* __restrict__ zout_b, float* __restrict__ zout_f,
    const int* __restrict__ offs, const int2* __restrict__ csr)
{
    int gid  = blockIdx.x * 256 + threadIdx.x;
    int node = gid >> 6;
    int lane = gid & 63;
    if (node >= NN) return;

    const ushort_t* zl = zin + lane;

    int beg = offs[node];
    int end = offs[node + 1];
    float acc = 0.f;
    int j = beg;

    for (; j + 8 <= end; j += 8) {
        int2 e0 = ldnt_e(csr + j);     int2 e1 = ldnt_e(csr + j + 1);
        int2 e2 = ldnt_e(csr + j + 2); int2 e3 = ldnt_e(csr + j + 3);
        int2 e4 = ldnt_e(csr + j + 4); int2 e5 = ldnt_e(csr + j + 5);
        int2 e6 = ldnt_e(csr + j + 6); int2 e7 = ldnt_e(csr + j + 7);
        float v0 = bf2f(zl[(size_t)e0.x * 64]);
        float v1 = bf2f(zl[(size_t)e1.x * 64]);
        float v2 = bf2f(zl[(size_t)e2.x * 64]);
        float v3 = bf2f(zl[(size_t)e3.x * 64]);
        float v4 = bf2f(zl[(size_t)e4.x * 64]);
        float v5 = bf2f(zl[(size_t)e5.x * 64]);
        float v6 = bf2f(zl[(size_t)e6.x * 64]);
        float v7 = bf2f(zl[(size_t)e7.x * 64]);
        acc = fmaf(__int_as_float(e0.y), v0, acc);
        acc = fmaf(__int_as_float(e1.y), v1, acc);
        acc = fmaf(__int_as_float(e2.y), v2, acc);
        acc = fmaf(__int_as_float(e3.y), v3, acc);
        acc = fmaf(__int_as_float(e4.y), v4, acc);
        acc = fmaf(__int_as_float(e5.y), v5, acc);
        acc = fmaf(__int_as_float(e6.y), v6, acc);
        acc = fmaf(__int_as_float(e7.y), v7, acc);
    }
    for (; j < end; ++j) {
        int2 e = ldnt_e(csr + j);
        acc = fmaf(__int_as_float(e.y), bf2f(zl[(size_t)e.x * 64]), acc);
    }

    float out = acc + bf2f(az0[(size_t)node * 64 + lane]);

    if (LSM) {
        float m = out;
#pragma unroll
        for (int o = 32; o > 0; o >>= 1) m = fmaxf(m, __shfl_xor(m, o, 64));
        float e = __expf(out - m);
        float s = e;
#pragma unroll
        for (int o = 32; o > 0; o >>= 1) s += __shfl_xor(s, o, 64);
        zout_f[(size_t)node * 64 + lane] = (out - m) - __logf(s);
    } else {
        zout_b[(size_t)node * 64 + lane] = f2bf(out);
    }
}

// ---------------------------------------------------------------------------
extern "C" void kernel_launch(void* const* d_in, const int* in_sizes, int n_in,
                              void* d_out, int out_size, void* d_ws, size_t ws_size,
                              hipStream_t stream)
{
    const float* x  = (const float*)d_in[0];
    const int*   ei = (const int*)  d_in[1];
    const float* ew = (const float*)d_in[2];
    const float* W1 = (const float*)d_in[3];
    const float* W2 = (const float*)d_in[4];
    const int* src = ei;
    const int* dst = ei + EE;

    char* ws = (char*)d_ws;
    size_t off = 0;
    auto alloc = [&](size_t bytes) -> char* {
        char* p = ws + off;
        off += (bytes + 255) & ~(size_t)255;
        return p;
    };

    float*    h     = (float*)   alloc((size_t)NN * HIDN * 4);  // 25.6 MB; -> csr
    ushort_t* zbA   = (ushort_t*)alloc((size_t)NN * NCLS * 2);  // 12.8 MB (bf16 z0)
    ushort_t* zbB   = (ushort_t*)alloc((size_t)NN * NCLS * 2);  // 12.8 MB
    ushort_t* az0   = (ushort_t*)alloc((size_t)NN * NCLS * 2);  // 12.8 MB (bf16 a*z0)
    int*      deg   = (int*)     alloc((size_t)NN * 4);
    int*      offs  = (int*)     alloc((size_t)(NN + 1) * 4);
    int*      cur_  = (int*)     alloc((size_t)NN * 4);
    int*      bsum  = (int*)     alloc((size_t)NB * 4);
    int*      bbase = (int*)     alloc((size_t)NB * 4);

    int2* csr = (int2*)h;       // h dead after GEMM2

    // feature transform (gemm2 fuses bf16 z0 + alpha*z0 epilogue)
    gemm_kernel<true><<<(NN + 63) / 64, 256, 0, stream>>>(x, W1, h, NN, NF);
    gemm2_kernel<<<(NN + 63) / 64, 256, 0, stream>>>(h, W2, zbA, az0, NN, HIDN);

    // CSR build
    zero_kernel<<<(NN + 255) / 256, 256, 0, stream>>>(deg, NN);
    count_kernel<<<EE / 256, 256, 0, stream>>>(dst, deg);
    scanA_kernel<<<NB, 256, 0, stream>>>(deg, bsum);
    scanB_kernel<<<1, 256, 0, stream>>>(bsum, bbase, offs);
    scanC_kernel<<<NB, 256, 0, stream>>>(deg, bbase, offs, cur_);
    scatter_kernel<<<SC_BLOCKS, 256, 0, stream>>>(src, dst, ew, cur_, csr);

    // 10 power iterations, bf16 ping-pong; final emits fp32 log_softmax
    const ushort_t* cur = zbA;
    ushort_t* nxt = zbB;
    for (int it = 0; it < 9; ++it) {
        propagate_kernel<false><<<(NN * 64) / 256, 256, 0, stream>>>(
            cur, az0, nxt, nullptr, offs, csr);
        ushort_t* t = (ushort_t*)cur; cur = nxt; nxt = t;
    }
    propagate_kernel<true><<<(NN * 64) / 256, 256, 0, stream>>>(
        cur, az0, nullptr, (float*)d_out, offs, csr);
}